// Round 2
// 550.906 us; speedup vs baseline: 1.0975x; 1.0975x over previous
//
#include <hip/hip_runtime.h>
#include <hip/hip_bf16.h>
#include <math.h>

typedef __bf16 bf16_t;
typedef __bf16 bf16x4_t __attribute__((ext_vector_type(4)));
typedef __bf16 bf16x8_t __attribute__((ext_vector_type(8)));
typedef float  f32x4    __attribute__((ext_vector_type(4)));

#define NE  8
#define NR  16
#define ND  2048
#define NH  8192
#define NT  4096
#define NER 128              // NE*NR
#define NK1 (ND + NER)       // 2176
#define NK2 (NH + NER)       // 8320

// gelu_new via sigmoid: 0.5x(1+tanh(u)) == x * sigmoid(2u)
static __device__ __forceinline__ float gelu_fast(float x) {
    const float c2 = 1.5957691216057308f;  // 2*sqrt(2/pi)
    float u2 = c2 * (x + 0.044715f * x * x * x);
    return x / (1.0f + __expf(-u2));
}

static __device__ __forceinline__ void load16_to_lds(const bf16_t* g, bf16_t* l) {
    __builtin_amdgcn_global_load_lds(
        (__attribute__((address_space(1))) void*)(g),
        (__attribute__((address_space(3))) void*)(l),
        16, 0, 0);
}

// ---------------------------------------------------------------------------
// x fp32 -> Xaug1[:, 0:ND] bf16  (8 elems/thread)
// ---------------------------------------------------------------------------
__global__ __launch_bounds__(256) void conv_x(
    const float* __restrict__ x, bf16_t* __restrict__ Xa1)
{
    const int i  = blockIdx.x * 256 + threadIdx.x;   // < NT*ND/8
    const int row = i >> 8;                          // ND/8 = 256
    const int c8  = i & 255;
    f32x4 v0 = *(const f32x4*)(x + (long)i * 8);
    f32x4 v1 = *(const f32x4*)(x + (long)i * 8 + 4);
    bf16x8_t o = {(bf16_t)v0[0], (bf16_t)v0[1], (bf16_t)v0[2], (bf16_t)v0[3],
                  (bf16_t)v1[0], (bf16_t)v1[1], (bf16_t)v1[2], (bf16_t)v1[3]};
    *(bf16x8_t*)(Xa1 + (long)row * NK1 + (c8 << 3)) = o;
}

// fp32 [nrows][K0] -> bf16 [nrows][ld], 8 elems/thread; shift8 = log2(K0/8)
__global__ __launch_bounds__(256) void prep_main(
    const float* __restrict__ W, bf16_t* __restrict__ Waug,
    int ld, int shift8, int total8)
{
    const int i = blockIdx.x * 256 + threadIdx.x;
    if (i >= total8) return;
    const int row = i >> shift8;
    const int c8  = i & ((1 << shift8) - 1);
    f32x4 v0 = *(const f32x4*)(W + (long)i * 8);
    f32x4 v1 = *(const f32x4*)(W + (long)i * 8 + 4);
    bf16x8_t o = {(bf16_t)v0[0], (bf16_t)v0[1], (bf16_t)v0[2], (bf16_t)v0[3],
                  (bf16_t)v1[0], (bf16_t)v1[1], (bf16_t)v1[2], (bf16_t)v1[3]};
    *(bf16x8_t*)(Waug + (long)row * ld + (c8 << 3)) = o;
}

// lora region: Waug[row][K0 + e*16 + r] = Blora[e][row][r]
__global__ __launch_bounds__(256) void prep_lora(
    const float* __restrict__ Bl, bf16_t* __restrict__ Waug,
    int nrows, int K0, int ld, int total)
{
    const int i = blockIdx.x * 256 + threadIdx.x;
    if (i >= total) return;
    const int row = i >> 7;
    const int c   = i & 127;
    const int e   = c >> 4;
    const int r   = c & 15;
    float v = Bl[((long)e * nrows + row) * NR + r];
    Waug[(long)row * ld + K0 + c] = (bf16_t)v;
}

// split-K reduce for LoRA: sum partials, expert-mask, *2, -> bf16 lora cols
template <int SPLITS, int LD>
__global__ __launch_bounds__(256) void zred(
    const float* __restrict__ zp, const int* __restrict__ eidx,
    bf16_t* __restrict__ dst)
{
    const int i = blockIdx.x * 256 + threadIdx.x;  // < NT*128
    const int t = i >> 7;
    const int c = i & 127;
    float s = 0.f;
#pragma unroll
    for (int j = 0; j < SPLITS; ++j) s += zp[(long)j * NT * 128 + i];
    const int e = eidx[t];
    float v = ((c >> 4) == e) ? 2.0f * s : 0.f;
    dst[(long)t * LD + c] = (bf16_t)v;
}

// ---------------------------------------------------------------------------
// Legacy 2-phase bf16 GEMM, kept ONLY for the LoRA split-K path (MODE 3).
// ---------------------------------------------------------------------------
template <int BM, int BN, int W, int WM, int WN,
          int K, int LDA, int LDB, int LDC, int MODE>
__global__ __launch_bounds__(W * 64) void gemm_bt(
    const bf16_t* __restrict__ A,  const bf16_t* __restrict__ Bt,
    const float* __restrict__ bias, void* __restrict__ Cout)
{
    constexpr int RW  = BM / WM;
    constexpr int CW  = BN / WN;
    constexpr int MT  = RW / 16;
    constexpr int NTn = CW / 16;
    constexpr int AI  = BM / 16 / W;
    constexpr int BI  = BN / 16 / W;

    __shared__ union {
        struct { bf16_t As[2 * BM * 32]; bf16_t Bs[2 * BN * 32]; } s;
        bf16_t Cs[64 * 264];
    } u;

    const int tid   = threadIdx.x;
    const int wave  = tid >> 6;
    const int lane  = tid & 63;
    const int col16 = lane & 15;
    const int q     = lane >> 4;
    const int wm    = wave % WM;
    const int wn    = wave / WM;

    const int  rowA0 = blockIdx.y * BM;
    const int  colB0 = (MODE == 3) ? 0 : blockIdx.x * BN;
    const long koff  = (MODE == 3) ? (long)blockIdx.x * K : 0;

    const int srow  = lane >> 2;
    const int skoff = (lane & 3) * 8;

    const bf16_t* Agp[AI][2];
    const bf16_t* Bgp[BI][2];
    bf16_t*       AsD[AI][2];
    bf16_t*       BsD[BI][2];
#pragma unroll
    for (int jj = 0; jj < AI; ++jj) {
        const int j = (wave + jj * W) * 16;
#pragma unroll
        for (int h = 0; h < 2; ++h) {
            Agp[jj][h] = A + (long)(rowA0 + j + srow) * LDA + koff + h * 32 + skoff;
            AsD[jj][h] = &u.s.As[(h * BM + j) * 32];
        }
    }
#pragma unroll
    for (int jj = 0; jj < BI; ++jj) {
        const int j = (wave + jj * W) * 16;
#pragma unroll
        for (int h = 0; h < 2; ++h) {
            Bgp[jj][h] = Bt + (long)(colB0 + j + srow) * LDB + koff + h * 32 + skoff;
            BsD[jj][h] = &u.s.Bs[(h * BN + j) * 32];
        }
    }

    const bf16_t* Ard = &u.s.As[(wm * RW + col16) * 32 + q * 8];
    const bf16_t* Brd = &u.s.Bs[(wn * CW + col16) * 32 + q * 8];

    f32x4 acc[MT][NTn];
#pragma unroll
    for (int i = 0; i < MT; ++i)
#pragma unroll
        for (int j = 0; j < NTn; ++j)
            acc[i][j] = (f32x4){0.f, 0.f, 0.f, 0.f};

    for (int it = 0; it < K / 64; ++it) {
#pragma unroll
        for (int jj = 0; jj < AI; ++jj)
#pragma unroll
            for (int h = 0; h < 2; ++h) {
                load16_to_lds(Agp[jj][h], AsD[jj][h]);
                Agp[jj][h] += 64;
            }
#pragma unroll
        for (int jj = 0; jj < BI; ++jj)
#pragma unroll
            for (int h = 0; h < 2; ++h) {
                load16_to_lds(Bgp[jj][h], BsD[jj][h]);
                Bgp[jj][h] += 64;
            }
        __syncthreads();

#pragma unroll
        for (int h = 0; h < 2; ++h) {
            bf16x8_t af[MT], bfr[NTn];
#pragma unroll
            for (int mt = 0; mt < MT; ++mt)
                af[mt] = *(const bf16x8_t*)(Ard + (h * BM + mt * 16) * 32);
#pragma unroll
            for (int nt = 0; nt < NTn; ++nt)
                bfr[nt] = *(const bf16x8_t*)(Brd + (h * BN + nt * 16) * 32);
#pragma unroll
            for (int mt = 0; mt < MT; ++mt)
#pragma unroll
                for (int nt = 0; nt < NTn; ++nt)
                    acc[mt][nt] = __builtin_amdgcn_mfma_f32_16x16x32_bf16(
                        af[mt], bfr[nt], acc[mt][nt], 0, 0, 0);
        }
        __syncthreads();
    }

    if (MODE == 3) {
        float* Cf = (float*)Cout + (long)blockIdx.x * NT * LDC;
#pragma unroll
        for (int nt = 0; nt < NTn; ++nt) {
            const int col = wn * CW + nt * 16 + col16;
#pragma unroll
            for (int mt = 0; mt < MT; ++mt) {
                const int row0 = rowA0 + wm * RW + mt * 16 + q * 4;
#pragma unroll
                for (int i = 0; i < 4; ++i)
                    Cf[(long)(row0 + i) * LDC + col] = acc[mt][nt][i];
            }
        }
    }
}

// ---------------------------------------------------------------------------
// 8-phase 256-row-tile bf16 GEMM: T2 swizzle + T3/T4 counted vmcnt + T5.
// C[m][n] = sum_k A[m][k] * Bt[n][k].  BM=256 fixed, BK=64 as 2 k-halves.
// LDS ring: A half-slots [parity][kh] 4 x 16 KiB, B half-slots 4 x BN*64 B.
// Half-tile = full rows x 32-k.  Staging: 1 half per phase of tile t+1;
// waits are vmcnt(LA+LB) at phases 2 & 4 only (never drain-0 in the loop).
// LDS k-seg swizzle: seg' = seg ^ ((row>>1)&3)  (conflict-free ds_read_b128,
// applied on BOTH the pre-swizzled global source and the read offset).
// MODE 0: +bias, gelu -> bf16 (LDS repack).  MODE 1: +bias -> fp32.
// ---------------------------------------------------------------------------

#define BARRIER8() do { __builtin_amdgcn_sched_barrier(0); \
    __builtin_amdgcn_s_barrier(); \
    __builtin_amdgcn_sched_barrier(0); } while (0)

#define WAITLG8() do { asm volatile("s_waitcnt lgkmcnt(0)" ::: "memory"); \
    __builtin_amdgcn_sched_barrier(0); } while (0)

template <int N>
static __device__ __forceinline__ void wait_vm() {
    static_assert(N == 0 || N == 3 || N == 4, "unsupported vmcnt");
    if constexpr (N == 0) asm volatile("s_waitcnt vmcnt(0)" ::: "memory");
    if constexpr (N == 3) asm volatile("s_waitcnt vmcnt(3)" ::: "memory");
    if constexpr (N == 4) asm volatile("s_waitcnt vmcnt(4)" ::: "memory");
}

#define STAGE_A8(TT, KH) do { \
    char* ld_ = smem + (((((TT) & 1) << 1) + (KH)) * ASLOT) + sdW; \
    const bf16_t* g_ = gA + (long)(TT) * 64 + (KH) * 32; \
    _Pragma("unroll") \
    for (int j_ = 0; j_ < LA; ++j_) \
        load16_to_lds(g_ + (long)j_ * 128 * LDA_, (bf16_t*)(ld_ + j_ * 8192)); \
} while (0)

#define STAGE_B8(TT, KH) do { \
    char* ld_ = smem + BOFF0 + (((((TT) & 1) << 1) + (KH)) * BSLOT) + sdW; \
    const bf16_t* g_ = gB + (long)(TT) * 64 + (KH) * 32; \
    _Pragma("unroll") \
    for (int j_ = 0; j_ < LB; ++j_) \
        load16_to_lds(g_ + (long)j_ * 128 * LDB_, (bf16_t*)(ld_ + j_ * 8192)); \
} while (0)

#define RD_A8(RP, KH, MH) do { \
    const char* p_ = smem + (((RP) * 2 + (KH)) * ASLOT) \
                   + (wm * RW + (MH) * (RW / 2)) * 64 + rdoff; \
    _Pragma("unroll") \
    for (int mt_ = 0; mt_ < MT2; ++mt_) \
        af[mt_] = *(const bf16x8_t*)(p_ + mt_ * 1024); \
} while (0)

#define RD_B8(RP, KH) do { \
    const char* p_ = smem + BOFF0 + (((RP) * 2 + (KH)) * BSLOT) \
                   + (wn * CW) * 64 + rdoff; \
    _Pragma("unroll") \
    for (int nt_ = 0; nt_ < NTn; ++nt_) \
        bfr[nt_] = *(const bf16x8_t*)(p_ + nt_ * 1024); \
} while (0)

#define MFMA_PH8(MH) do { \
    __builtin_amdgcn_s_setprio(1); \
    _Pragma("unroll") \
    for (int mt_ = 0; mt_ < MT2; ++mt_) \
        _Pragma("unroll") \
        for (int nt_ = 0; nt_ < NTn; ++nt_) \
            acc[(MH) * MT2 + mt_][nt_] = __builtin_amdgcn_mfma_f32_16x16x32_bf16( \
                af[mt_], bfr[nt_], acc[(MH) * MT2 + mt_][nt_], 0, 0, 0); \
    __builtin_amdgcn_s_setprio(0); \
} while (0)

// One K-tile = 4 phases: (kh0,mh0)(kh0,mh1)(kh1,mh0)(kh1,mh1).
// ST_ is a compile-time literal 0/1.
#define TILE8(T_, ST_) do { \
    const int rp_ = (T_) & 1; \
    /* ph1 */ \
    RD_A8(rp_, 0, 0); RD_B8(rp_, 0); \
    if (ST_) STAGE_A8((T_) + 1, 0); \
    BARRIER8(); WAITLG8(); MFMA_PH8(0); BARRIER8(); \
    /* ph2 */ \
    RD_A8(rp_, 0, 1); \
    if (ST_) { STAGE_B8((T_) + 1, 0); wait_vm<LA + LB>(); } \
    else     { wait_vm<0>(); } \
    BARRIER8(); WAITLG8(); MFMA_PH8(1); BARRIER8(); \
    /* ph3 */ \
    RD_A8(rp_, 1, 0); RD_B8(rp_, 1); \
    if (ST_) STAGE_A8((T_) + 1, 1); \
    BARRIER8(); WAITLG8(); MFMA_PH8(0); BARRIER8(); \
    /* ph4 */ \
    RD_A8(rp_, 1, 1); \
    if (ST_) { STAGE_B8((T_) + 1, 1); wait_vm<LA + LB>(); } \
    BARRIER8(); WAITLG8(); MFMA_PH8(1); BARRIER8(); \
} while (0)

template <int BN, int WM, int WN, int KT, int LDA_, int LDB_, int LDC_, int MODE>
__global__ __launch_bounds__(512, 2) void gemm8(
    const bf16_t* __restrict__ A, const bf16_t* __restrict__ Bt,
    const float* __restrict__ bias, void* __restrict__ Cout)
{
    constexpr int BM    = 256;
    constexpr int RW    = BM / WM;     // rows per wave
    constexpr int CW    = BN / WN;     // cols per wave
    constexpr int MT    = RW / 16;     // m-tiles per wave
    constexpr int MT2   = MT / 2;      // m-tiles per phase
    constexpr int NTn   = CW / 16;     // n-tiles per wave
    constexpr int LA    = 2;           // A gload_lds per thread per half
    constexpr int LB    = BN / 128;    // B gload_lds per thread per half
    constexpr int NTIL  = KT / 64;
    constexpr int ASLOT = 16384;       // 256 rows x 32 k x 2B
    constexpr int BSLOT = BN * 64;
    constexpr int BOFF0 = 4 * ASLOT;
    constexpr int RING  = BOFF0 + 4 * BSLOT;
    constexpr int CSB   = 64 * 264 * 2;
    constexpr int SMEM  = (MODE == 0 && CSB > RING) ? CSB : RING;

    __shared__ __align__(16) char smem[SMEM];

    const int tid   = threadIdx.x;
    const int wave  = tid >> 6;
    const int lane  = tid & 63;
    const int col16 = lane & 15;
    const int q     = lane >> 4;
    const int wm    = wave % WM;
    const int wn    = wave / WM;

    const int rowA0 = blockIdx.y * BM;
    const int colB0 = blockIdx.x * BN;

    // staging: per-thread global src (pre-swizzled k-seg), wave-uniform LDS dst
    const int srow = tid >> 2;                      // 0..127
    const int sseg = (tid & 3) ^ ((tid >> 3) & 3);  // seg ^ ((row>>1)&3)
    const bf16_t* gA = A  + (long)(rowA0 + srow) * LDA_ + sseg * 8;
    const bf16_t* gB = Bt + (long)(colB0 + srow) * LDB_ + sseg * 8;
    const int sdW = wave << 10;

    // ds_read: per-lane swizzled byte offset within a half-slot
    const int rdoff = col16 * 64 + ((q ^ ((lane >> 1) & 3)) << 4);

    bf16x8_t af[MT2];
    bf16x8_t bfr[NTn];
    f32x4 acc[MT][NTn];
#pragma unroll
    for (int i = 0; i < MT; ++i)
#pragma unroll
        for (int j = 0; j < NTn; ++j)
            acc[i][j] = (f32x4){0.f, 0.f, 0.f, 0.f};

    // prologue: stage tile 0 fully; kh0 must land (kh1 may stay in flight)
    STAGE_A8(0, 0); STAGE_B8(0, 0); STAGE_A8(0, 1); STAGE_B8(0, 1);
    wait_vm<LA + LB>();
    BARRIER8();

    for (int t = 0; t < NTIL - 1; ++t) TILE8(t, 1);
    TILE8(NTIL - 1, 0);

    if (MODE == 1) {
        float* Cf = (float*)Cout;
#pragma unroll
        for (int nt = 0; nt < NTn; ++nt) {
            const int col = colB0 + wn * CW + nt * 16 + col16;
            const float bv = bias[col];
#pragma unroll
            for (int mt = 0; mt < MT; ++mt) {
                const int row0 = rowA0 + wm * RW + mt * 16 + q * 4;
#pragma unroll
                for (int i = 0; i < 4; ++i)
                    Cf[(long)(row0 + i) * LDC_ + col] = acc[mt][nt][i] + bv;
            }
        }
    } else {
        // MODE 0: gelu -> bf16 via LDS repack, 64-row phases, 16B stores.
        // All gload_lds drained by the final tile's ph2 vmcnt(0); ring is dead.
        bf16_t* Cb = (bf16_t*)Cout;
        bf16_t* Cs = (bf16_t*)smem;
#pragma unroll
        for (int ph = 0; ph < BM / 64; ++ph) {
            const int phwm = (ph * 64) / RW;
            const int mtb  = ((ph * 64) % RW) / 16;
            if (wm == phwm) {
#pragma unroll
                for (int nt = 0; nt < NTn; ++nt) {
                    const int c = wn * CW + nt * 16 + col16;
                    const float bv = bias[colB0 + c];
#pragma unroll
                    for (int mt = 0; mt < 4; ++mt) {
                        const int rl = mt * 16 + q * 4;
#pragma unroll
                        for (int i = 0; i < 4; ++i)
                            Cs[(rl + i) * 264 + c] =
                                (bf16_t)gelu_fast(acc[mtb + mt][nt][i] + bv);
                    }
                }
            }
            __syncthreads();
            {
                constexpr int CPR = BN / 32;
                const int r  = tid / CPR;
                const int c0 = (tid % CPR) * 32;
                const long gbase =
                    (long)(rowA0 + ph * 64 + r) * LDC_ + colB0 + c0;
#pragma unroll
                for (int ch = 0; ch < 4; ++ch) {
                    bf16x8_t v = *(const bf16x8_t*)&Cs[r * 264 + c0 + ch * 8];
                    *(bf16x8_t*)&Cb[gbase + ch * 8] = v;
                }
            }
            __syncthreads();
        }
    }
}

// ---------------------------------------------------------------------------
extern "C" void kernel_launch(void* const* d_in, const int* in_sizes, int n_in,
                              void* d_out, int out_size, void* d_ws, size_t ws_size,
                              hipStream_t stream)
{
    const float* x    = (const float*)d_in[0];
    const int*   eidx = (const int*)  d_in[1];
    const float* W1   = (const float*)d_in[2];
    const float* b1   = (const float*)d_in[3];
    const float* A1   = (const float*)d_in[4];
    const float* B1   = (const float*)d_in[5];
    const float* W2   = (const float*)d_in[6];
    const float* b2   = (const float*)d_in[7];
    const float* A2   = (const float*)d_in[8];
    const float* B2   = (const float*)d_in[9];
    float* out = (float*)d_out;

    char* ws = (char*)d_ws;
    bf16_t* Xaug2 = (bf16_t*)(ws);
    bf16_t* Xaug1 = (bf16_t*)(ws + 68157440L);
    bf16_t* W1aug = (bf16_t*)(ws + 85983232L);
    bf16_t* W2aug = (bf16_t*)(ws + 68157440L);
    bf16_t* A1b   = (bf16_t*)(ws + 104000000L);
    bf16_t* A2b   = (bf16_t*)(ws + 104857600L);
    float*  zp1   = (float*) (ws + 106954752L);
    float*  zp2   = (float*) (ws + 85983232L);

    // --- layer 1 ---
    conv_x<<<NT * ND / 8 / 256, 256, 0, stream>>>(x, Xaug1);
    prep_main<<<(NER * ND / 8) / 256, 256, 0, stream>>>(A1, A1b, ND, 8, NER * ND / 8);
    {   // LoRA1 split-K: 4 chunks x K=512 (legacy 2-phase kernel)
        dim3 g(4, NT / 128);
        gemm_bt<128, 128, 4, 2, 2, 512, NK1, ND, 128, 3><<<g, 256, 0, stream>>>(
            Xaug1, A1b, nullptr, (void*)zp1);
    }
    zred<4, NK1><<<NT * 128 / 256, 256, 0, stream>>>(zp1, eidx, Xaug1 + ND);
    prep_main<<<(NH * ND / 8) / 256, 256, 0, stream>>>(W1, W1aug, NK1, 8, NH * ND / 8);
    prep_lora<<<(NH * NER) / 256, 256, 0, stream>>>(B1, W1aug, NH, ND, NK1, NH * NER);
    {   // GEMM1: y = gelu(Xaug1 @ W1aug^T + b1) -> Xaug2[:, 0:NH] bf16
        //         256x256 8-phase, 512 threads, 512 blocks
        dim3 g(NH / 256, NT / 256);
        gemm8<256, 2, 4, NK1, NK1, NK1, NK2, 0><<<g, 512, 0, stream>>>(
            Xaug1, W1aug, b1, (void*)Xaug2);
    }

    // --- layer 2 ---
    prep_main<<<(NER * NH / 8) / 256, 256, 0, stream>>>(A2, A2b, NH, 10, NER * NH / 8);
    {   // LoRA2 split-K: 8 chunks x K=1024 (legacy 2-phase kernel)
        dim3 g(8, NT / 128);
        gemm_bt<128, 128, 4, 2, 2, 1024, NK2, NH, 128, 3><<<g, 256, 0, stream>>>(
            Xaug2, A2b, nullptr, (void*)zp2);
    }
    zred<8, NK2><<<NT * 128 / 256, 256, 0, stream>>>(zp2, eidx, Xaug2 + NH);
    prep_main<<<(ND * NH / 8) / 256, 256, 0, stream>>>(W2, W2aug, NK2, 10, ND * NH / 8);
    prep_lora<<<(ND * NER) / 256, 256, 0, stream>>>(B2, W2aug, ND, NH, NK2, ND * NER);
    {   // GEMM2: out = Xaug2 @ W2aug^T + b2 (fp32), 256x128 8-phase, 256 blocks
        dim3 g(ND / 128, NT / 256);
        gemm8<128, 4, 2, NK2, NK2, NK2, ND, 1><<<g, 512, 0, stream>>>(
            Xaug2, W2aug, b2, (void*)out);
    }
}